// Round 8
// baseline (798.250 us; speedup 1.0000x reference)
//
#include <hip/hip_runtime.h>

#define T_ENC 20
#define T_DEC 30
#define WAVES 4            // 4 waves/block (256 thr)
#define EPW 64             // 64 batch elements per wave = 2 groups of 32
#define EPB (WAVES * EPW)  // 256 elements per block

typedef __attribute__((ext_vector_type(8))) _Float16 half8;  // 8 f16 = 4 VGPR
typedef __attribute__((ext_vector_type(16))) float f32x16;   // MFMA 32x32 acc

#if __has_builtin(__builtin_amdgcn_exp2f)
#define EXP2F(x) __builtin_amdgcn_exp2f(x)
#else
#define EXP2F(x) exp2f(x)
#endif
#if __has_builtin(__builtin_amdgcn_rcpf)
#define RCPF(x) __builtin_amdgcn_rcpf(x)
#else
#define RCPF(x) (1.0f / (x))
#endif

#define LOG2E 1.4426950408889634f
#define TWO_LOG2E 2.8853900817779268f

#define MFMA16(a, b, c) __builtin_amdgcn_mfma_f32_32x32x16_f16(a, b, c, 0, 0, 0)

__device__ __forceinline__ unsigned short h2u(_Float16 h) {
  union { _Float16 h; unsigned short u; } v;
  v.h = h;
  return v.u;
}

// (256,1): only config that avoids arch-VGPR starvation (R3-R6 all spilled at
// 2 waves/EU budgets). Occupancy is HW-capped at 1 wave/SIMD by the unified
// VGPR+AGPR footprint (~512/wave), so we fill stalls with 2-group ILP instead.
__global__ __launch_bounds__(256, 1)
void SinglePrediction_88493506167138_kernel(
    const float* __restrict__ x,         // [B][20][2]
    const float* __restrict__ W_ih_enc,  // [256][2]
    const float* __restrict__ W_hh_enc,  // [256][64]
    const float* __restrict__ b_ih_enc,  // [256]
    const float* __restrict__ b_hh_enc,  // [256]
    const float* __restrict__ W_ih_dec,  // [256][64]
    const float* __restrict__ W_hh_dec,  // [256][64]
    const float* __restrict__ b_ih_dec,  // [256]
    const float* __restrict__ b_hh_dec,  // [256]
    const float* __restrict__ W_emb,     // [2][64]
    const float* __restrict__ b_emb,     // [2]
    float* __restrict__ out,             // [B][30][2]
    float* __restrict__ ws,              // [30][B][2] staging (if use_ws)
    int Btot, int use_ws)
{
  // LDS: 36864 (W) + 8192 (Wx x-chunk) + 2*32768 (hT hi/lo, 2 groups/wave)
  //      + 1024 (bias) = 111,616 B -> 1 block/CU, grid 256 = exact fit
  __shared__ __align__(16) unsigned short Wf[288 * 64];
  __shared__ __align__(16) unsigned short Wx[256 * 16];
  __shared__ __align__(16) unsigned short hTh[WAVES][2][32 * 64];
  __shared__ __align__(16) unsigned short hTl[WAVES][2][32 * 64];
  __shared__ float bsum_l[256];

  const int tid = threadIdx.x;
  const int lane = tid & 63;
  const int wid = tid >> 6;
  const int hi5 = lane >> 5;
  const int l31 = lane & 31;
  const int beb = blockIdx.x * EPB;

  // ---- stage encoder W_hh * gate-scale as fp16, XOR-swizzled ----
  for (int i = tid; i < 256 * 64; i += 256) {
    int row = i >> 6, k = i & 63;
    float sc = ((row >> 6) == 2) ? TWO_LOG2E : LOG2E;  // g-gate rows get 2L
    Wf[(row << 6) | (k ^ ((row & 7) << 3))] = h2u((_Float16)(W_hh_enc[i] * sc));
  }
  // ---- stage x-chunk: row r, k: [W0, W1, W0, W1, 0 x12] (A = x hi/lo) ----
  for (int i = tid; i < 256 * 16; i += 256) {
    int r = i >> 4, k = i & 15;
    float sc = ((r >> 6) == 2) ? TWO_LOG2E : LOG2E;
    float v = (k < 4) ? W_ih_enc[2 * r + (k & 1)] * sc : 0.f;
    Wx[i] = h2u((_Float16)v);
  }
  if (tid < 256) {
    float sc = ((tid >> 6) == 2) ? TWO_LOG2E : LOG2E;
    bsum_l[tid] = (b_ih_enc[tid] + b_hh_enc[tid]) * sc;
  }
  // ---- zero this wave's hT (h0 = 0), both groups ----
  {
    float4 z = {0.f, 0.f, 0.f, 0.f};
    float4* p0 = (float4*)&hTh[wid][0][0];
    float4* p1 = (float4*)&hTl[wid][0][0];
    for (int i = lane; i < 512; i += 64) { p0[i] = z; p1[i] = z; }
  }
  __syncthreads();

  float biasv[8];
#pragma unroll
  for (int nt = 0; nt < 8; nt++) biasv[nt] = bsum_l[nt * 32 + l31];

  float cA[2][16], cB[2][16];
#pragma unroll
  for (int p = 0; p < 2; p++)
#pragma unroll
    for (int q = 0; q < 16; q++) { cA[p][q] = 0.f; cB[p][q] = 0.f; }

  const int sw = (l31 & 7) << 3;  // swizzle term (same for A and B)
  const int kbase = hi5 << 3;     // k-offset of this lane half

  half8 ahA[4], alA[4], ahB[4], alB[4];
  auto loadA = [&]() {
#pragma unroll
    for (int kt = 0; kt < 4; kt++) {
      int sk = (kt * 16 + kbase) ^ sw;
      ahA[kt] = *(const half8*)&hTh[wid][0][(l31 << 6) + sk];
      alA[kt] = *(const half8*)&hTl[wid][0][(l31 << 6) + sk];
      ahB[kt] = *(const half8*)&hTh[wid][1][(l31 << 6) + sk];
      alB[kt] = *(const half8*)&hTl[wid][1][(l31 << 6) + sk];
    }
  };

  // shared-B gates GEMM: per W fragment, 4 MFMAs (2 groups x h hi/lo)
  auto gemm_main = [&](f32x16 (&aA)[8], f32x16 (&aB)[8]) {
#pragma unroll
    for (int kt = 0; kt < 4; kt++) {
      const int sk = (kt * 16 + kbase) ^ sw;
#pragma unroll
      for (int nt = 0; nt < 8; nt++) {
        const half8 b = *(const half8*)&Wf[((nt * 32 + l31) << 6) + sk];
        aA[nt] = MFMA16(ahA[kt], b, aA[nt]);
        aB[nt] = MFMA16(ahB[kt], b, aB[nt]);
        aA[nt] = MFMA16(alA[kt], b, aA[nt]);
        aB[nt] = MFMA16(alB[kt], b, aB[nt]);
      }
    }
  };

  // gates pre-scaled by log2e (2*log2e for g) -> exp2 direct
  auto finish = [&](f32x16 (&acc)[8], float (&c)[2][16], int g) {
#pragma unroll
    for (int p = 0; p < 2; p++)
#pragma unroll
      for (int q = 0; q < 16; q++) {
        float ig = RCPF(1.f + EXP2F(-acc[0 + p][q]));
        float fg = RCPF(1.f + EXP2F(-acc[2 + p][q]));
        float eg = EXP2F(acc[4 + p][q]);
        float gg = 1.f - 2.f * RCPF(eg + 1.f);
        float og = RCPF(1.f + EXP2F(-acc[6 + p][q]));
        float cn = fmaf(fg, c[p][q], ig * gg);
        c[p][q] = cn;
        float ec = EXP2F(TWO_LOG2E * cn);
        float th = 1.f - 2.f * RCPF(ec + 1.f);
        float hn = og * th;
        _Float16 hh = (_Float16)hn;
        _Float16 hl = (_Float16)(hn - (float)hh);
        const int row = (q & 3) + 8 * (q >> 2) + 4 * hi5;
        const int col = l31 + 32 * p;
        const int si = (row << 6) | (col ^ ((row & 7) << 3));
        hTh[wid][g][si] = h2u(hh);
        hTl[wid][g][si] = h2u(hl);
      }
  };

  // ================= encoder =================
#pragma unroll 1
  for (int t = 0; t < T_ENC; t++) {
    loadA();
    f32x16 accA[8], accB[8];
#pragma unroll
    for (int nt = 0; nt < 8; nt++)
#pragma unroll
      for (int q = 0; q < 16; q++) { accA[nt][q] = biasv[nt]; accB[nt][q] = biasv[nt]; }
    // x-chunk: lane supplies x for batch row l31 (A-operand layout); the
    // hi5=1 half contributes zeros (B rows k>=4 are zeroed too)
    const float m = (hi5 == 0) ? 1.f : 0.f;
    const float2 xA =
        *(const float2*)&x[((size_t)(beb + wid * EPW + l31)) * 40 + 2 * t];
    const float2 xB =
        *(const float2*)&x[((size_t)(beb + wid * EPW + 32 + l31)) * 40 + 2 * t];
    const float xA0 = xA.x * m, xA1 = xA.y * m;
    const float xB0 = xB.x * m, xB1 = xB.y * m;
    _Float16 a0h = (_Float16)xA0, a1h = (_Float16)xA1;
    _Float16 a0l = (_Float16)(xA0 - (float)a0h), a1l = (_Float16)(xA1 - (float)a1h);
    _Float16 b0h = (_Float16)xB0, b1h = (_Float16)xB1;
    _Float16 b0l = (_Float16)(xB0 - (float)b0h), b1l = (_Float16)(xB1 - (float)b1h);
    const half8 a5A = {a0h, a1h, a0l, a1l, (_Float16)0.f, (_Float16)0.f, (_Float16)0.f, (_Float16)0.f};
    const half8 a5B = {b0h, b1h, b0l, b1l, (_Float16)0.f, (_Float16)0.f, (_Float16)0.f, (_Float16)0.f};
#pragma unroll
    for (int nt = 0; nt < 8; nt++) {
      const half8 bx = *(const half8*)&Wx[((nt * 32 + l31) << 4) + kbase];
      accA[nt] = MFMA16(a5A, bx, accA[nt]);
      accB[nt] = MFMA16(a5B, bx, accB[nt]);
    }
    gemm_main(accA, accB);
    finish(accA, cA, 0);
    finish(accB, cB, 1);
  }

  // ================= swap to decoder weights (+ W_emb rows 256..287) =======
  __syncthreads();
  for (int i = tid; i < 288 * 64; i += 256) {
    int row = i >> 6, k = i & 63;
    float w;
    if (row < 256) {
      float sc = ((row >> 6) == 2) ? TWO_LOG2E : LOG2E;
      w = (W_ih_dec[i] + W_hh_dec[i]) * sc;  // dec input == h: fold ih+hh
    } else if (row < 258) {
      w = W_emb[(row - 256) * 64 + k];       // unscaled
    } else {
      w = 0.f;
    }
    Wf[(row << 6) | (k ^ ((row & 7) << 3))] = h2u((_Float16)w);
  }
  if (tid < 256) {
    float sc = ((tid >> 6) == 2) ? TWO_LOG2E : LOG2E;
    bsum_l[tid] = (b_ih_dec[tid] + b_hh_dec[tid]) * sc;
  }
  __syncthreads();

#pragma unroll
  for (int nt = 0; nt < 8; nt++) biasv[nt] = bsum_l[nt * 32 + l31];
  const float bev = (l31 == 0) ? b_emb[0] : b_emb[1];

  // pos_{tout} from current A-frags (h after step tout+1): 9th N-tile MFMA
  auto do_pos = [&](half8 (&ah)[4], half8 (&al)[4], int gofs, int tout) {
    f32x16 accP;
#pragma unroll
    for (int q = 0; q < 16; q++) accP[q] = 0.f;
#pragma unroll
    for (int kt = 0; kt < 4; kt++) {
      int sk = (kt * 16 + kbase) ^ sw;
      int r = 256 + l31;
      half8 be = *(const half8*)&Wf[(r << 6) + sk];
      accP = MFMA16(ah[kt], be, accP);
      accP = MFMA16(al[kt], be, accP);
    }
    if (l31 < 2) {
#pragma unroll
      for (int q = 0; q < 16; q++) {
        int row = (q & 3) + 8 * (q >> 2) + 4 * hi5;
        size_t e = (size_t)(beb + wid * EPW + gofs + row);
        float v = accP[q] + bev;
        if (use_ws) {
          ws[((size_t)tout * Btot + e) * 2 + l31] = v;  // [T][B][2] WC-friendly
        } else {
          out[e * 60 + 2 * tout + l31] = v;
        }
      }
    }
  };

  // ================= decoder =================
#pragma unroll 1
  for (int t = 0; t < T_DEC; t++) {
    loadA();
    if (t > 0) {
      do_pos(ahA, alA, 0, t - 1);
      do_pos(ahB, alB, 32, t - 1);
    }
    f32x16 accA[8], accB[8];
#pragma unroll
    for (int nt = 0; nt < 8; nt++)
#pragma unroll
      for (int q = 0; q < 16; q++) { accA[nt][q] = biasv[nt]; accB[nt][q] = biasv[nt]; }
    gemm_main(accA, accB);
    finish(accA, cA, 0);
    finish(accB, cB, 1);
  }
  loadA();
  do_pos(ahA, alA, 0, T_DEC - 1);
  do_pos(ahB, alB, 32, T_DEC - 1);
}

// ws [30][B][2] -> out [B][30][2]; reads coalesced, per-thread writes cover
// a contiguous 240 B span (wave covers 15 KB fully -> write-combine in L2)
__global__ __launch_bounds__(256)
void pos_transpose_kernel(const float* __restrict__ ws,
                          float* __restrict__ out, int Btot) {
  const int e = blockIdx.x * 256 + threadIdx.x;
  float2 v[T_DEC];
#pragma unroll
  for (int t = 0; t < T_DEC; t++)
    v[t] = ((const float2*)ws)[(size_t)t * Btot + e];
  float2* o = (float2*)(out + (size_t)e * 60);
#pragma unroll
  for (int t = 0; t < T_DEC; t++) o[t] = v[t];
}

extern "C" void kernel_launch(void* const* d_in, const int* in_sizes, int n_in,
                              void* d_out, int out_size, void* d_ws, size_t ws_size,
                              hipStream_t stream) {
  const float* x        = (const float*)d_in[0];
  const float* W_ih_enc = (const float*)d_in[1];
  const float* W_hh_enc = (const float*)d_in[2];
  const float* b_ih_enc = (const float*)d_in[3];
  const float* b_hh_enc = (const float*)d_in[4];
  const float* W_ih_dec = (const float*)d_in[5];
  const float* W_hh_dec = (const float*)d_in[6];
  const float* b_ih_dec = (const float*)d_in[7];
  const float* b_hh_dec = (const float*)d_in[8];
  const float* W_emb    = (const float*)d_in[9];
  const float* b_emb    = (const float*)d_in[10];
  float* out = (float*)d_out;

  const int B = in_sizes[0] / (T_ENC * 2);  // 65536
  const int grid = B / EPB;                 // 256 = exactly 1 block per CU
  const size_t ws_needed = (size_t)B * T_DEC * 2 * sizeof(float);
  const int use_ws = (ws_size >= ws_needed) ? 1 : 0;

  hipLaunchKernelGGL(SinglePrediction_88493506167138_kernel,
                     dim3(grid), dim3(256), 0, stream,
                     x, W_ih_enc, W_hh_enc, b_ih_enc, b_hh_enc,
                     W_ih_dec, W_hh_dec, b_ih_dec, b_hh_dec,
                     W_emb, b_emb, out, (float*)d_ws, B, use_ws);
  if (use_ws) {
    hipLaunchKernelGGL(pos_transpose_kernel, dim3(B / 256), dim3(256), 0,
                       stream, (const float*)d_ws, out, B);
  }
}